// Round 6
// baseline (3007.567 us; speedup 1.0000x reference)
//
#include <hip/hip_runtime.h>
#include <hip/hip_bf16.h>

// Problem: B=32, T=128, I=H=O=512, L=2, bidirectional GRU + FC head.
// ws layout (bytes):
//   proj (bf16): [2][128][32][1536]            = 12,582,912 elems * 2B = 25.17 MB
//   seq  (fp32): [2][128][32][512]             =  4,194,304 elems * 4B = 16.78 MB
//   slabs(fp32): [2l][2d][128jb][6144]         =  6,291,456 elems * 4B = 25.17 MB
// total 67.12 MB; sync slots live in __device__ globals (zeroed by repack each launch)
#define PROJ_ELEMS 12582912
#define SEQ_ELEMS  4194304
#define SLAB_PER_BLK 6144

typedef float f32x4 __attribute__((ext_vector_type(4)));

// Producer-keyed dataflow slots: g_slots[ld*128 + jb] = epoch published by block
// (d,jb) of layer ld: value t+1 means h(t) for columns [4jb,4jb+4) is LLC-visible.
// All traffic RELAXED agent-scope (sc1) — no wbl2/inv. Monotonic, no reset.
__device__ unsigned g_slots[512];

// ---------------- proj GEMM: [8192 x 1536] = src @ [Wxh | Wxr] + bias -> bf16 ----------------
// grid (12, 64), block 256. 128x128 tile, 8x8 per-thread register tile.
__global__ __launch_bounds__(256)
void proj_kernel(const float* __restrict__ src,
                 const float* __restrict__ Wxh, const float* __restrict__ bxh,
                 const float* __restrict__ Wxr, const float* __restrict__ bxr,
                 __hip_bfloat16* __restrict__ proj, int layer)
{
    __shared__ float As[32][137];   // [k][row] transposed A tile
    __shared__ float Ws[32][132];   // [k][col]
    const int tid  = threadIdx.x;
    const int col0 = blockIdx.x * 128;
    const int row0 = blockIdx.y * 128;
    const int d    = row0 >> 12;              // rows 0..4095 = dir0, 4096..8191 = dir1
    const int ld   = layer * 2 + d;
    const int tx = tid & 15, ty = tid >> 4;

    const bool is_xr = (col0 >= 1024);
    const float* Wbase = is_xr ? (Wxr + (size_t)ld * 512 * 512 + (col0 - 1024))
                               : (Wxh + (size_t)ld * 512 * 1024 + col0);
    const int wstride = is_xr ? 512 : 1024;
    const float* bias = is_xr ? (bxr + ld * 512 + (col0 - 1024))
                              : (bxh + ld * 1024 + col0);

    float acc[8][8];
    #pragma unroll
    for (int i = 0; i < 8; i++)
        #pragma unroll
        for (int j = 0; j < 8; j++) acc[i][j] = 0.f;

    for (int k0 = 0; k0 < 512; k0 += 32) {
        #pragma unroll
        for (int v = 0; v < 4; v++) {
            int idx = tid + v * 256;
            int r   = idx >> 3;
            int c4  = (idx & 7) << 2;
            int gm  = row0 + r;
            int rr  = gm & 4095;
            int tt  = rr >> 5, bb = rr & 31;
            const float* p;
            if (layer == 0) {
                int ts = (gm >= 4096) ? (127 - tt) : tt;  // dir1 reads reversed time
                p = src + ((size_t)bb * 128 + ts) * 512 + (k0 + c4);
            } else {
                p = src + (((size_t)(gm >> 12) * 128 + tt) * 32 + bb) * 512 + (k0 + c4);
            }
            float4 vv = *(const float4*)p;
            As[c4 + 0][r] = vv.x; As[c4 + 1][r] = vv.y;
            As[c4 + 2][r] = vv.z; As[c4 + 3][r] = vv.w;
        }
        #pragma unroll
        for (int v = 0; v < 4; v++) {
            int idx = tid + v * 256;
            int kr  = idx >> 5;
            int c4  = (idx & 31) << 2;
            *(float4*)&Ws[kr][c4] = *(const float4*)(Wbase + (size_t)(k0 + kr) * wstride + c4);
        }
        __syncthreads();
        #pragma unroll
        for (int kk = 0; kk < 32; kk++) {
            float a[8], w[8];
            *(float4*)&a[0] = *(const float4*)&As[kk][ty * 8];
            *(float4*)&a[4] = *(const float4*)&As[kk][ty * 8 + 4];
            *(float4*)&w[0] = *(const float4*)&Ws[kk][tx * 8];
            *(float4*)&w[4] = *(const float4*)&Ws[kk][tx * 8 + 4];
            #pragma unroll
            for (int i = 0; i < 8; i++)
                #pragma unroll
                for (int j = 0; j < 8; j++)
                    acc[i][j] += a[i] * w[j];
        }
        __syncthreads();
    }
    #pragma unroll
    for (int i = 0; i < 8; i++) {
        int gm = row0 + ty * 8 + i;
        __hip_bfloat16* dst = proj + (size_t)gm * 1536 + col0 + tx * 8;
        #pragma unroll
        for (int j = 0; j < 8; j++)
            dst[j] = __float2bfloat16(acc[i][j] + bias[tx * 8 + j]);
    }
}

// ---------------- weight repack: per-(ld,jb) contiguous slab ----------------
// slab[(ld*128+jb)][idx], idx = (g*4+cg)*12 + e*4 + ki ; k = g*4+ki, j = jb*4+cg
// e: 0 = Whh z-col j, 1 = Whh r-col 512+j, 2 = Whr g-col j.
// Also zeroes the dataflow slots (must run before the gru kernels).
__global__ __launch_bounds__(256)
void repack_kernel(const float* __restrict__ Whh, const float* __restrict__ Whr,
                   float* __restrict__ slabs)
{
    if (blockIdx.x == 0) {
        g_slots[threadIdx.x] = 0u;
        g_slots[threadIdx.x + 256] = 0u;
    }
    const int blk = blockIdx.x;           // 0..511 = ld*128 + jb
    const int ld = blk >> 7, jb = blk & 127;
    const float* WhhL = Whh + (size_t)ld * 512 * 1024;
    const float* WhrL = Whr + (size_t)ld * 512 * 512;
    float* out = slabs + (size_t)blk * SLAB_PER_BLK;
    for (int u = 0; u < 24; u++) {
        int idx = threadIdx.x + u * 256;  // 0..6143
        int rec = idx / 12, r3 = idx % 12;
        int g = rec >> 2, cg = rec & 3;
        int e = r3 >> 2, ki = r3 & 3;
        int k = g * 4 + ki, j = jb * 4 + cg;
        float v;
        if (e == 0)      v = WhhL[(size_t)k * 1024 + j];
        else if (e == 1) v = WhhL[(size_t)k * 1024 + 512 + j];
        else             v = WhrL[(size_t)k * 512 + j];
        out[idx] = v;
    }
}

// ---------------- fused GRU sequence: all 128 timesteps, one launch ----------------
// grid 256 = d*128 + jb (4 j-cols each), block 256 = (b = tid>>3, kh = bit2, cg = tid&3).
// R6 sync: NO grid barrier. seq is t-indexed (never overwritten), so the only
// dependency is read-after-publish. Thread's 16 staging loads all come from producer
// jb = tid&127, so each wave __all-polls just its 64 producers' slots and stages the
// moment they are ready — wait overlaps staging, and the post-store barrier round
// trip is gone. Ordering chain unchanged from the proven R4/R5 pattern:
// sc1 h-stores -> __syncthreads (vmcnt drain) -> sc1 publish -> consumer poll ->
// control-dependent sc1 staging loads.
// R6 weights: wz/wr in LDS as compact 8-float records with the kh=1 half shifted
// +16B: wave bank starts = cgi*8 + kh*4 -> all 32 banks tiled exactly once,
// conflict-free single-phase reads (R5's layout paid 1 conflict-cycle per read).
// wg streams from the global slab (24 KB, L1-resident) to run on the TA pipe in
// parallel with the saturated DS pipe. LDS: 64 KB hs + 16.4 KB wlds -> 1 block/CU.
__global__ __launch_bounds__(256)
void gru_seq_kernel(const __hip_bfloat16* __restrict__ proj, float* __restrict__ seq,
                    const float* __restrict__ slabs,
                    const float* __restrict__ bhh, const float* __restrict__ bhr,
                    int layer)
{
    __shared__ __align__(16) float hs[32 * 512];   // h swizzled: [b][(g^(b&7))*4 + ki]
    __shared__ __align__(16) float wlds[4100];     // wz/wr compact, kh=1 half +4 floats
    const int tid = threadIdx.x;
    const int d   = blockIdx.x >> 7;
    const int jb  = blockIdx.x & 127;
    const int ld  = layer * 2 + d;
    const int cgi = tid & 3;
    const int kh  = (tid >> 2) & 1;
    const int b   = tid >> 3;
    const int j   = jb * 4 + cgi;
    const int sb  = b & 7;

    // loop invariants, loaded once per layer
    const f32x4* wrec = (const f32x4*)slabs + (size_t)(ld * 128 + jb) * 1536;
    const float bz = bhh[ld * 1024 + j];
    const float br = bhh[ld * 1024 + 512 + j];
    const float bg = bhr[ld * 512 + j];
    const float* hbase = seq + (size_t)(d * 128) * 32 * 512;
    const __hip_bfloat16* pbase = proj + ((size_t)(d * 128) * 32 + b) * 1536 + j;
    float* wout = seq + ((size_t)(d * 128) * 32 + b) * 512 + j;
    unsigned* slot_base = &g_slots[ld * 128];
    unsigned* myslot = slot_base + (tid & 127);   // this thread's staging producer

    // one-time: stage wz/wr into compact LDS layout. i = rec*2 + e (rec=g*4+cg,
    // e in {0,1}); dest shifted +1 float4 for the kh=1 half (rec>=256 <=> i>=512).
    #pragma unroll
    for (int u = 0; u < 4; u++) {
        int i = tid + u * 256;               // 0..1023
        ((f32x4*)wlds)[i + (i >= 512 ? 1 : 0)] = wrec[(i >> 1) * 3 + (i & 1)];
    }

    // software-pipelined proj load for t=0 (read-only data, normal cached loads)
    __hip_bfloat16 rz = pbase[0], rr_ = pbase[512], rg = pbase[1024];

    for (int t = 0; t < 128; ++t) {
        if (t > 0) {
            // wait for THIS thread's producer (wave-granular: __all over 64 slots),
            // then stage h(t-1) -> LDS with the proven XOR-on-float4-slot swizzle.
            const unsigned tgt = (unsigned)t;
            for (;;) {
                unsigned s = __hip_atomic_load(myslot, __ATOMIC_RELAXED,
                                               __HIP_MEMORY_SCOPE_AGENT);
                if (__all(s >= tgt)) break;
                __builtin_amdgcn_s_sleep(1);
            }
            const float* hsrc = hbase + (size_t)(t - 1) * 32 * 512;
            f32x4 tmp[16];
            #pragma unroll
            for (int v = 0; v < 16; v++) {
                int id = tid + v * 256;           // float4 id 0..4095
                asm volatile("global_load_dwordx4 %0, %1, off sc0 sc1"
                             : "=v"(tmp[v])
                             : "v"((const void*)(hsrc + (size_t)id * 4)));
            }
            asm volatile("s_waitcnt vmcnt(0)" ::: "memory");
            #pragma unroll
            for (int v = 0; v < 16; v++) {
                int id = tid + v * 256;
                int bb = id >> 7, g = id & 127;
                *(f32x4*)&hs[bb * 512 + ((g ^ (bb & 7)) << 2)] = tmp[v];
            }
        }
        __syncthreads();   // full h tile staged (and wlds visible at t=0)

        float pz = __bfloat162float(rz);
        float pr = __bfloat162float(rr_);
        float pg = __bfloat162float(rg);

        float az = 0.f, ar = 0.f, ag = 0.f;
        float hv_self = 0.f;
        if (t > 0) {
            #pragma unroll 4
            for (int gg = 0; gg < 64; gg++) {
                int g = kh * 64 + gg;
                int rec = g * 4 + cgi;
                float4 h4 = *(const float4*)&hs[b * 512 + ((g ^ sb) << 2)];
                const f32x4* wp = (const f32x4*)wlds + (rec << 1) + kh;
                f32x4 wz = wp[0], wr = wp[1];     // LDS, conflict-free
                f32x4 wg = wrec[rec * 3 + 2];     // global slab, L1-resident
                az += h4.x * wz.x + h4.y * wz.y + h4.z * wz.z + h4.w * wz.w;
                ar += h4.x * wr.x + h4.y * wr.y + h4.z * wr.z + h4.w * wr.w;
                ag += h4.x * wg.x + h4.y * wg.y + h4.z * wg.z + h4.w * wg.w;
            }
            // combine the two k-halves (lanes differ in bit 2)
            az += __shfl_xor(az, 4, 64);
            ar += __shfl_xor(ar, 4, 64);
            ag += __shfl_xor(ag, 4, 64);
            hv_self = hs[b * 512 + ((jb ^ sb) << 2) + cgi];   // g_self = j>>2 = jb
        }

        float z  = 1.f / (1.f + __expf(-(az + pz + bz)));
        float r  = 1.f / (1.f + __expf(-(ar + pr + br)));
        float gt = tanhf((ag + bg) * r + pg);
        float hn = z * hv_self + (1.f - z) * gt;
        if (kh == 0)   // coherent (sc1) write-through so other XCDs' sc1 loads see it
            __hip_atomic_store(wout + (size_t)t * 32 * 512, hn,
                               __ATOMIC_RELAXED, __HIP_MEMORY_SCOPE_AGENT);

        // ---- publish h(t): visible to every consumer of columns [4jb,4jb+4) ----
        if (t < 127) {
            __syncthreads();   // each wave drains vmcnt(0): all sc1 h-stores visible
            if (tid == 0)      // relaxed slot store (sc1) — no wbl2
                __hip_atomic_store(slot_base + jb, (unsigned)(t + 1),
                                   __ATOMIC_RELAXED, __HIP_MEMORY_SCOPE_AGENT);
            // prefetch next-step proj; overlaps the next wait (registers survive)
            const __hip_bfloat16* pn = pbase + (size_t)(t + 1) * 32 * 1536;
            rz = pn[0]; rr_ = pn[512]; rg = pn[1024];
        }
    }
}

// ---------------- final FC ----------------
__global__ __launch_bounds__(256)
void fc_kernel(const float* __restrict__ seq, const float* __restrict__ Wfc,
               const float* __restrict__ bfc, float* __restrict__ out)
{
    int idx = blockIdx.x * 256 + threadIdx.x;   // 0..16383
    int b = idx >> 9, o = idx & 511;
    const float* catf = seq + ((size_t)(0 * 128 + 127) * 32 + b) * 512;  // fwd, t=127
    const float* catr = seq + ((size_t)(1 * 128 + 0) * 32 + b) * 512;    // rev, t=0
    float acc = bfc[o];
    #pragma unroll 8
    for (int k = 0; k < 512; k++) acc += catf[k] * Wfc[(size_t)k * 512 + o];
    #pragma unroll 8
    for (int k = 0; k < 512; k++) acc += catr[k] * Wfc[(size_t)(512 + k) * 512 + o];
    out[(size_t)b * 512 + o] = acc;
}

extern "C" void kernel_launch(void* const* d_in, const int* in_sizes, int n_in,
                              void* d_out, int out_size, void* d_ws, size_t ws_size,
                              hipStream_t stream) {
    (void)in_sizes; (void)n_in; (void)out_size; (void)ws_size;
    const float* x   = (const float*)d_in[0];
    const float* Wxh = (const float*)d_in[1];
    const float* bxh = (const float*)d_in[2];
    const float* Whh = (const float*)d_in[3];
    const float* bhh = (const float*)d_in[4];
    const float* Wxr = (const float*)d_in[5];
    const float* bxr = (const float*)d_in[6];
    const float* Whr = (const float*)d_in[7];
    const float* bhr = (const float*)d_in[8];
    const float* Wfc = (const float*)d_in[9];
    const float* bfc = (const float*)d_in[10];
    float* out = (float*)d_out;

    char* base = (char*)d_ws;
    __hip_bfloat16* proj = (__hip_bfloat16*)base;
    float* seq   = (float*)(base + (size_t)PROJ_ELEMS * 2);
    float* slabs = seq + SEQ_ELEMS;

    repack_kernel<<<512, 256, 0, stream>>>(Whh, Whr, slabs);

    dim3 pgrid(12, 64);
    proj_kernel<<<pgrid, 256, 0, stream>>>(x, Wxh, bxh, Wxr, bxr, proj, 0);
    {
        int layer = 0;
        void* args[] = {(void*)&proj, (void*)&seq, (void*)&slabs,
                        (void*)&bhh, (void*)&bhr, (void*)&layer};
        hipLaunchCooperativeKernel((void*)gru_seq_kernel, dim3(256), dim3(256),
                                   args, 0, stream);
    }
    proj_kernel<<<pgrid, 256, 0, stream>>>(seq, Wxh, bxh, Wxr, bxr, proj, 1);
    {
        int layer = 1;
        void* args[] = {(void*)&proj, (void*)&seq, (void*)&slabs,
                        (void*)&bhh, (void*)&bhr, (void*)&layer};
        hipLaunchCooperativeKernel((void*)gru_seq_kernel, dim3(256), dim3(256),
                                   args, 0, stream);
    }
    fc_kernel<<<64, 256, 0, stream>>>(seq, Wfc, bfc, out);
}

// Round 7
// 2608.579 us; speedup vs baseline: 1.1530x; 1.1530x over previous
//
#include <hip/hip_runtime.h>
#include <hip/hip_bf16.h>

// Problem: B=32, T=128, I=H=O=512, L=2, bidirectional GRU + FC head.
// ws layout (bytes):
//   proj (bf16): [2][128][32][1536]            = 12,582,912 elems * 2B = 25.17 MB
//   seq  (fp32): [2][128][32][512]             =  4,194,304 elems * 4B = 16.78 MB
//   slabs(fp32): [2l][2d][128jb][6144]         =  6,291,456 elems * 4B = 25.17 MB
// total 67.12 MB; sync slots live in __device__ globals (zeroed by repack each launch)
#define PROJ_ELEMS 12582912
#define SEQ_ELEMS  4194304
#define SLAB_PER_BLK 6144

typedef float f32x4 __attribute__((ext_vector_type(4)));

// Producer-keyed dataflow slots: g_slots[ld*128 + jb] = epoch published by block
// (d,jb) of layer ld: value t+1 means h(t) for columns [4jb,4jb+4) is LLC-visible.
// All traffic RELAXED agent-scope (sc1) — no wbl2/inv. Monotonic, no reset.
__device__ unsigned g_slots[512];

// ---------------- proj GEMM: [8192 x 1536] = src @ [Wxh | Wxr] + bias -> bf16 ----------------
// grid (12, 64), block 256. 128x128 tile, 8x8 per-thread register tile.
__global__ __launch_bounds__(256)
void proj_kernel(const float* __restrict__ src,
                 const float* __restrict__ Wxh, const float* __restrict__ bxh,
                 const float* __restrict__ Wxr, const float* __restrict__ bxr,
                 __hip_bfloat16* __restrict__ proj, int layer)
{
    __shared__ float As[32][137];   // [k][row] transposed A tile
    __shared__ float Ws[32][132];   // [k][col]
    const int tid  = threadIdx.x;
    const int col0 = blockIdx.x * 128;
    const int row0 = blockIdx.y * 128;
    const int d    = row0 >> 12;              // rows 0..4095 = dir0, 4096..8191 = dir1
    const int ld   = layer * 2 + d;
    const int tx = tid & 15, ty = tid >> 4;

    const bool is_xr = (col0 >= 1024);
    const float* Wbase = is_xr ? (Wxr + (size_t)ld * 512 * 512 + (col0 - 1024))
                               : (Wxh + (size_t)ld * 512 * 1024 + col0);
    const int wstride = is_xr ? 512 : 1024;
    const float* bias = is_xr ? (bxr + ld * 512 + (col0 - 1024))
                              : (bxh + ld * 1024 + col0);

    float acc[8][8];
    #pragma unroll
    for (int i = 0; i < 8; i++)
        #pragma unroll
        for (int j = 0; j < 8; j++) acc[i][j] = 0.f;

    for (int k0 = 0; k0 < 512; k0 += 32) {
        #pragma unroll
        for (int v = 0; v < 4; v++) {
            int idx = tid + v * 256;
            int r   = idx >> 3;
            int c4  = (idx & 7) << 2;
            int gm  = row0 + r;
            int rr  = gm & 4095;
            int tt  = rr >> 5, bb = rr & 31;
            const float* p;
            if (layer == 0) {
                int ts = (gm >= 4096) ? (127 - tt) : tt;  // dir1 reads reversed time
                p = src + ((size_t)bb * 128 + ts) * 512 + (k0 + c4);
            } else {
                p = src + (((size_t)(gm >> 12) * 128 + tt) * 32 + bb) * 512 + (k0 + c4);
            }
            float4 vv = *(const float4*)p;
            As[c4 + 0][r] = vv.x; As[c4 + 1][r] = vv.y;
            As[c4 + 2][r] = vv.z; As[c4 + 3][r] = vv.w;
        }
        #pragma unroll
        for (int v = 0; v < 4; v++) {
            int idx = tid + v * 256;
            int kr  = idx >> 5;
            int c4  = (idx & 31) << 2;
            *(float4*)&Ws[kr][c4] = *(const float4*)(Wbase + (size_t)(k0 + kr) * wstride + c4);
        }
        __syncthreads();
        #pragma unroll
        for (int kk = 0; kk < 32; kk++) {
            float a[8], w[8];
            *(float4*)&a[0] = *(const float4*)&As[kk][ty * 8];
            *(float4*)&a[4] = *(const float4*)&As[kk][ty * 8 + 4];
            *(float4*)&w[0] = *(const float4*)&Ws[kk][tx * 8];
            *(float4*)&w[4] = *(const float4*)&Ws[kk][tx * 8 + 4];
            #pragma unroll
            for (int i = 0; i < 8; i++)
                #pragma unroll
                for (int j = 0; j < 8; j++)
                    acc[i][j] += a[i] * w[j];
        }
        __syncthreads();
    }
    #pragma unroll
    for (int i = 0; i < 8; i++) {
        int gm = row0 + ty * 8 + i;
        __hip_bfloat16* dst = proj + (size_t)gm * 1536 + col0 + tx * 8;
        #pragma unroll
        for (int j = 0; j < 8; j++)
            dst[j] = __float2bfloat16(acc[i][j] + bias[tx * 8 + j]);
    }
}

// ---------------- weight repack: per-(ld,jb) contiguous slab ----------------
// slab[(ld*128+jb)][idx], idx = (g*4+cg)*12 + e*4 + ki ; k = g*4+ki, j = jb*4+cg
// e: 0 = Whh z-col j, 1 = Whh r-col 512+j, 2 = Whr g-col j.
// Also zeroes the dataflow slots (must run before the gru kernels).
__global__ __launch_bounds__(256)
void repack_kernel(const float* __restrict__ Whh, const float* __restrict__ Whr,
                   float* __restrict__ slabs)
{
    if (blockIdx.x == 0) {
        g_slots[threadIdx.x] = 0u;
        g_slots[threadIdx.x + 256] = 0u;
    }
    const int blk = blockIdx.x;           // 0..511 = ld*128 + jb
    const int ld = blk >> 7, jb = blk & 127;
    const float* WhhL = Whh + (size_t)ld * 512 * 1024;
    const float* WhrL = Whr + (size_t)ld * 512 * 512;
    float* out = slabs + (size_t)blk * SLAB_PER_BLK;
    for (int u = 0; u < 24; u++) {
        int idx = threadIdx.x + u * 256;  // 0..6143
        int rec = idx / 12, r3 = idx % 12;
        int g = rec >> 2, cg = rec & 3;
        int e = r3 >> 2, ki = r3 & 3;
        int k = g * 4 + ki, j = jb * 4 + cg;
        float v;
        if (e == 0)      v = WhhL[(size_t)k * 1024 + j];
        else if (e == 1) v = WhhL[(size_t)k * 1024 + 512 + j];
        else             v = WhrL[(size_t)k * 512 + j];
        out[idx] = v;
    }
}

// ---------------- fused GRU sequence: all 128 timesteps, one launch ----------------
// R7: 1024-thread blocks. R4/R5/R6 all sat at ~1300 us/layer with Occupancy 12%
// (= ONE wave/SIMD): the kernel was latency-bound — every DS/L1/LLC round-trip
// exposed. Same 256 blocks (d,jb), k now split 8-way: thread = (cgi=tid&3,
// kq=(tid>>2)&7, b=tid>>5), 16 gg iterations, three shfl_xor(4/8/16) combine the
// k-slices. 16 waves/block = 4 waves/SIMD -> 4-way TLP hides latency.
// hs swizzle gains a kq term: slot(b,g) = g ^ (b&7) ^ ((g>>4)&7), so a wave's 8
// kq-reads land on 8 distinct bank quads (old layout: 256B apart = same quad =
// 8-way conflict). Weight records (wz/wr compact in LDS, kh-half +16B) give 32
// distinct addrs = 4/quad on all 8 quads = the 4-cycle floor. wg streams from the
// L1-resident global slab (TA pipe, parallel with DS). Sync protocol unchanged
// (proven R4-R6): sc1 h-stores -> syncthreads vmcnt drain -> sc1 publish ->
// consumer poll -> control-dependent sc1 staging loads.
__global__ __launch_bounds__(1024, 4)
void gru_seq_kernel(const __hip_bfloat16* __restrict__ proj, float* __restrict__ seq,
                    const float* __restrict__ slabs,
                    const float* __restrict__ bhh, const float* __restrict__ bhr,
                    int layer)
{
    __shared__ __align__(16) float hs[32 * 512];   // h: [b][slot(b,g)*4 + ki]
    __shared__ __align__(16) float wlds[4100];     // wz/wr compact, kh=1 half +4 floats
    const int tid = threadIdx.x;
    const int d   = blockIdx.x >> 7;
    const int jb  = blockIdx.x & 127;
    const int ld  = layer * 2 + d;
    const int cgi = tid & 3;
    const int kq  = (tid >> 2) & 7;
    const int b   = tid >> 5;
    const int j   = jb * 4 + cgi;
    const int sb  = b & 7;

    // loop invariants, loaded once per layer
    const f32x4* wrec = (const f32x4*)slabs + (size_t)(ld * 128 + jb) * 1536;
    const float bz = bhh[ld * 1024 + j];
    const float br = bhh[ld * 1024 + 512 + j];
    const float bg = bhr[ld * 512 + j];
    const float* hbase = seq + (size_t)(d * 128) * 32 * 512;
    const __hip_bfloat16* pbase = proj + ((size_t)(d * 128) * 32 + b) * 1536 + j;
    float* wout = seq + ((size_t)(d * 128) * 32 + b) * 512 + j;
    unsigned* slot_base = &g_slots[ld * 128];
    unsigned* myslot = slot_base + (tid & 127);   // this thread's staging producer

    // one-time: stage wz/wr into compact LDS layout (1 float4 per thread).
    // i = rec*2 + e; dest shifted +1 float4 for the g>=64 half (i>=512).
    {
        int i = tid;                         // 0..1023
        ((f32x4*)wlds)[i + (i >= 512 ? 1 : 0)] = wrec[(i >> 1) * 3 + (i & 1)];
    }

    // software-pipelined proj load for t=0 (read-only data, normal cached loads)
    __hip_bfloat16 rz = pbase[0], rr_ = pbase[512], rg = pbase[1024];

    for (int t = 0; t < 128; ++t) {
        if (t > 0) {
            // wait for THIS thread's producer (wave-granular __all over 64 slots;
            // even waves poll jb 0..63, odd waves 64..127), then stage h(t-1).
            const unsigned tgt = (unsigned)t;
            for (;;) {
                unsigned s = __hip_atomic_load(myslot, __ATOMIC_RELAXED,
                                               __HIP_MEMORY_SCOPE_AGENT);
                if (__all(s >= tgt)) break;
                __builtin_amdgcn_s_sleep(1);
            }
            const float* hsrc = hbase + (size_t)(t - 1) * 32 * 512;
            f32x4 tmp[4];
            #pragma unroll
            for (int v = 0; v < 4; v++) {
                int id = tid + v * 1024;          // float4 id 0..4095
                asm volatile("global_load_dwordx4 %0, %1, off sc0 sc1"
                             : "=v"(tmp[v])
                             : "v"((const void*)(hsrc + (size_t)id * 4)));
            }
            asm volatile("s_waitcnt vmcnt(0)" ::: "memory");
            #pragma unroll
            for (int v = 0; v < 4; v++) {
                int id = tid + v * 1024;
                int bb = id >> 7, g = id & 127;
                int sl = g ^ (bb & 7) ^ ((g >> 4) & 7);
                *(f32x4*)&hs[bb * 512 + (sl << 2)] = tmp[v];
            }
        }
        __syncthreads();   // full h tile staged (and wlds visible at t=0)

        float pz = __bfloat162float(rz);
        float pr = __bfloat162float(rr_);
        float pg = __bfloat162float(rg);

        float az = 0.f, ar = 0.f, ag = 0.f;
        float hv_self = 0.f;
        if (t > 0) {
            #pragma unroll 4
            for (int gg = 0; gg < 16; gg++) {
                int g  = kq * 16 + gg;
                int sl = g ^ sb ^ kq;             // (g>>4)&7 == kq for this thread
                int rec = g * 4 + cgi;
                float4 h4 = *(const float4*)&hs[b * 512 + (sl << 2)];
                const f32x4* wp = (const f32x4*)wlds + (rec << 1) + (kq >> 2);
                f32x4 wz = wp[0], wr = wp[1];     // LDS, 4/quad on all 8 quads
                f32x4 wg = wrec[rec * 3 + 2];     // global slab, L1-resident
                az += h4.x * wz.x + h4.y * wz.y + h4.z * wz.z + h4.w * wz.w;
                ar += h4.x * wr.x + h4.y * wr.y + h4.z * wr.z + h4.w * wr.w;
                ag += h4.x * wg.x + h4.y * wg.y + h4.z * wg.z + h4.w * wg.w;
            }
            // combine the 8 k-slices (kq = lane bits 2..4)
            az += __shfl_xor(az, 4, 64);  ar += __shfl_xor(ar, 4, 64);  ag += __shfl_xor(ag, 4, 64);
            az += __shfl_xor(az, 8, 64);  ar += __shfl_xor(ar, 8, 64);  ag += __shfl_xor(ag, 8, 64);
            az += __shfl_xor(az, 16, 64); ar += __shfl_xor(ar, 16, 64); ag += __shfl_xor(ag, 16, 64);
            hv_self = hs[b * 512 + ((jb ^ sb ^ (jb >> 4)) << 2) + cgi];  // g_self = jb
        }

        float z  = 1.f / (1.f + __expf(-(az + pz + bz)));
        float r  = 1.f / (1.f + __expf(-(ar + pr + br)));
        float gt = tanhf((ag + bg) * r + pg);
        float hn = z * hv_self + (1.f - z) * gt;
        if (kq == 0)   // coherent (sc1) write-through so other XCDs' sc1 loads see it
            __hip_atomic_store(wout + (size_t)t * 32 * 512, hn,
                               __ATOMIC_RELAXED, __HIP_MEMORY_SCOPE_AGENT);

        // ---- publish h(t): visible to every consumer of columns [4jb,4jb+4) ----
        if (t < 127) {
            __syncthreads();   // each wave drains vmcnt(0): all sc1 h-stores visible
            if (tid == 0)      // relaxed slot store (sc1) — no wbl2
                __hip_atomic_store(slot_base + jb, (unsigned)(t + 1),
                                   __ATOMIC_RELAXED, __HIP_MEMORY_SCOPE_AGENT);
            // prefetch next-step proj; overlaps the next wait (registers survive)
            const __hip_bfloat16* pn = pbase + (size_t)(t + 1) * 32 * 1536;
            rz = pn[0]; rr_ = pn[512]; rg = pn[1024];
        }
    }
}

// ---------------- final FC ----------------
__global__ __launch_bounds__(256)
void fc_kernel(const float* __restrict__ seq, const float* __restrict__ Wfc,
               const float* __restrict__ bfc, float* __restrict__ out)
{
    int idx = blockIdx.x * 256 + threadIdx.x;   // 0..16383
    int b = idx >> 9, o = idx & 511;
    const float* catf = seq + ((size_t)(0 * 128 + 127) * 32 + b) * 512;  // fwd, t=127
    const float* catr = seq + ((size_t)(1 * 128 + 0) * 32 + b) * 512;    // rev, t=0
    float acc = bfc[o];
    #pragma unroll 8
    for (int k = 0; k < 512; k++) acc += catf[k] * Wfc[(size_t)k * 512 + o];
    #pragma unroll 8
    for (int k = 0; k < 512; k++) acc += catr[k] * Wfc[(size_t)(512 + k) * 512 + o];
    out[(size_t)b * 512 + o] = acc;
}

extern "C" void kernel_launch(void* const* d_in, const int* in_sizes, int n_in,
                              void* d_out, int out_size, void* d_ws, size_t ws_size,
                              hipStream_t stream) {
    (void)in_sizes; (void)n_in; (void)out_size; (void)ws_size;
    const float* x   = (const float*)d_in[0];
    const float* Wxh = (const float*)d_in[1];
    const float* bxh = (const float*)d_in[2];
    const float* Whh = (const float*)d_in[3];
    const float* bhh = (const float*)d_in[4];
    const float* Wxr = (const float*)d_in[5];
    const float* bxr = (const float*)d_in[6];
    const float* Whr = (const float*)d_in[7];
    const float* bhr = (const float*)d_in[8];
    const float* Wfc = (const float*)d_in[9];
    const float* bfc = (const float*)d_in[10];
    float* out = (float*)d_out;

    char* base = (char*)d_ws;
    __hip_bfloat16* proj = (__hip_bfloat16*)base;
    float* seq   = (float*)(base + (size_t)PROJ_ELEMS * 2);
    float* slabs = seq + SEQ_ELEMS;

    repack_kernel<<<512, 256, 0, stream>>>(Whh, Whr, slabs);

    dim3 pgrid(12, 64);
    proj_kernel<<<pgrid, 256, 0, stream>>>(x, Wxh, bxh, Wxr, bxr, proj, 0);
    {
        int layer = 0;
        void* args[] = {(void*)&proj, (void*)&seq, (void*)&slabs,
                        (void*)&bhh, (void*)&bhr, (void*)&layer};
        hipLaunchCooperativeKernel((void*)gru_seq_kernel, dim3(256), dim3(1024),
                                   args, 0, stream);
    }
    proj_kernel<<<pgrid, 256, 0, stream>>>(seq, Wxh, bxh, Wxr, bxr, proj, 1);
    {
        int layer = 1;
        void* args[] = {(void*)&proj, (void*)&seq, (void*)&slabs,
                        (void*)&bhh, (void*)&bhr, (void*)&layer};
        hipLaunchCooperativeKernel((void*)gru_seq_kernel, dim3(256), dim3(1024),
                                   args, 0, stream);
    }
    fc_kernel<<<64, 256, 0, stream>>>(seq, Wfc, bfc, out);
}